// Round 1
// baseline (308.953 us; speedup 1.0000x reference)
//
#include <hip/hip_runtime.h>
#include <hip/hip_bf16.h>

typedef __bf16 bf16x8 __attribute__((ext_vector_type(8)));
typedef float  f32x4  __attribute__((ext_vector_type(4)));

#define B_ROWS 4096
#define NROWS  8192
#define DDIM   512
// exp(sim/T) = exp2(sim * (1/T)/ln2), T=0.5 -> 2/ln2
#define SCALE2 2.8853900817779268f

// ---------------- normalize: fp32 rows -> bf16 normalized rows in ws ----------------
__global__ __launch_bounds__(256) void normalize_kernel(
    const float* __restrict__ h1, const float* __restrict__ h2,
    __bf16* __restrict__ zb) {
  int wave = threadIdx.x >> 6;
  int lane = threadIdx.x & 63;
  int row  = blockIdx.x * 4 + wave;
  const float* src = (row < B_ROWS) ? (h1 + (size_t)row * DDIM)
                                    : (h2 + (size_t)(row - B_ROWS) * DDIM);
  float4 v0 = *(const float4*)(src + lane * 8);
  float4 v1 = *(const float4*)(src + lane * 8 + 4);
  float ss = v0.x*v0.x + v0.y*v0.y + v0.z*v0.z + v0.w*v0.w
           + v1.x*v1.x + v1.y*v1.y + v1.z*v1.z + v1.w*v1.w;
  #pragma unroll
  for (int m = 1; m <= 32; m <<= 1) ss += __shfl_xor(ss, m);
  float scale = 1.0f / fmaxf(sqrtf(ss), 1e-8f);
  bf16x8 o;
  o[0] = (__bf16)(v0.x*scale); o[1] = (__bf16)(v0.y*scale);
  o[2] = (__bf16)(v0.z*scale); o[3] = (__bf16)(v0.w*scale);
  o[4] = (__bf16)(v1.x*scale); o[5] = (__bf16)(v1.y*scale);
  o[6] = (__bf16)(v1.z*scale); o[7] = (__bf16)(v1.w*scale);
  *(bf16x8*)(zb + (size_t)row * DDIM + lane * 8) = o;
}

// ---------------- fused sim GEMM + exp + row-sum ----------------
// grid (64, 64): 128x128 tile per block, 4 waves in 2x2, each wave 64x64 (4x4 MFMA tiles)
__global__ __launch_bounds__(256) void simexp_kernel(
    const __bf16* __restrict__ zb, float* __restrict__ rowsum) {
  __shared__ __align__(16) __bf16 As[128 * 32];
  __shared__ __align__(16) __bf16 Bs[128 * 32];

  const int tid  = threadIdx.x;
  const int wave = tid >> 6;
  const int lane = tid & 63;
  const int wm = wave >> 1, wn = wave & 1;
  const int quad = lane >> 4;
  const int l16  = lane & 15;
  const int rowBlk = blockIdx.y * 128;
  const int colBlk = blockIdx.x * 128;

  const int srow = lane >> 2;        // 0..15 (row within 16-row staging chunk)
  const int scol = (lane & 3) * 8;   // bf16 element offset within row

  f32x4 acc[4][4] = {};

  #pragma unroll 1
  for (int kt = 0; kt < 16; ++kt) {
    const int k0 = kt * 32;
    #pragma unroll
    for (int q = 0; q < 2; ++q) {
      const int rl = wave * 32 + q * 16;  // wave-uniform chunk base (16 rows)
      const __bf16* ga = zb + (size_t)(rowBlk + rl + srow) * DDIM + k0 + scol;
      const __bf16* gb = zb + (size_t)(colBlk + rl + srow) * DDIM + k0 + scol;
      __builtin_amdgcn_global_load_lds(
          (const __attribute__((address_space(1))) unsigned int*)ga,
          (__attribute__((address_space(3))) unsigned int*)(As + rl * 32), 16, 0, 0);
      __builtin_amdgcn_global_load_lds(
          (const __attribute__((address_space(1))) unsigned int*)gb,
          (__attribute__((address_space(3))) unsigned int*)(Bs + rl * 32), 16, 0, 0);
    }
    __syncthreads();

    bf16x8 afr[4], bfr[4];
    #pragma unroll
    for (int rt = 0; rt < 4; ++rt)
      afr[rt] = *(const bf16x8*)(As + (wm * 64 + rt * 16 + l16) * 32 + quad * 8);
    #pragma unroll
    for (int ct = 0; ct < 4; ++ct)
      bfr[ct] = *(const bf16x8*)(Bs + (wn * 64 + ct * 16 + l16) * 32 + quad * 8);
    #pragma unroll
    for (int rt = 0; rt < 4; ++rt)
      #pragma unroll
      for (int ct = 0; ct < 4; ++ct)
        acc[rt][ct] = __builtin_amdgcn_mfma_f32_16x16x32_bf16(
            afr[rt], bfr[ct], acc[rt][ct], 0, 0, 0);
    __syncthreads();
  }

  // epilogue: e = exp2(sim*SCALE2), mask diagonal, per-row partial sums
  // C/D layout (16x16x32): col = lane&15, row = quad*4 + reg  [m89/m91 verified]
  #pragma unroll
  for (int rt = 0; rt < 4; ++rt) {
    #pragma unroll
    for (int r = 0; r < 4; ++r) {
      const int grow = rowBlk + wm * 64 + rt * 16 + quad * 4 + r;
      float s = 0.f;
      #pragma unroll
      for (int ct = 0; ct < 4; ++ct) {
        const int gcol = colBlk + wn * 64 + ct * 16 + l16;
        float e = exp2f(acc[rt][ct][r] * SCALE2);
        s += (grow == gcol) ? 0.f : e;
      }
      s += __shfl_xor(s, 1);
      s += __shfl_xor(s, 2);
      s += __shfl_xor(s, 4);
      s += __shfl_xor(s, 8);
      if (l16 == 0) atomicAdd(&rowsum[grow], s);
    }
  }
}

// ---------------- finalize: loss_i = ln(rowsum_i) - 2*pos_i ; mean ----------------
__global__ __launch_bounds__(256) void finalize_kernel(
    const __bf16* __restrict__ zb, const float* __restrict__ rowsum,
    float* __restrict__ out) {
  int wave = threadIdx.x >> 6;
  int lane = threadIdx.x & 63;
  int row = blockIdx.x * 4 + wave;
  int partner = (row + B_ROWS) & (NROWS - 1);
  bf16x8 va = *(const bf16x8*)(zb + (size_t)row * DDIM + lane * 8);
  bf16x8 vb = *(const bf16x8*)(zb + (size_t)partner * DDIM + lane * 8);
  float dot = 0.f;
  #pragma unroll
  for (int j = 0; j < 8; ++j) dot += (float)va[j] * (float)vb[j];
  #pragma unroll
  for (int m = 1; m <= 32; m <<= 1) dot += __shfl_xor(dot, m);
  if (lane == 0) {
    float loss = __logf(rowsum[row]) - 2.0f * dot;
    atomicAdd(out, loss * (1.0f / NROWS));
  }
}

extern "C" void kernel_launch(void* const* d_in, const int* in_sizes, int n_in,
                              void* d_out, int out_size, void* d_ws, size_t ws_size,
                              hipStream_t stream) {
  const float* h1 = (const float*)d_in[0];
  const float* h2 = (const float*)d_in[1];
  float* out = (float*)d_out;
  __bf16* zb = (__bf16*)d_ws;                                        // 8 MiB
  float* rowsum = (float*)((char*)d_ws + (size_t)NROWS * DDIM * 2);  // 32 KiB

  hipMemsetAsync(rowsum, 0, NROWS * sizeof(float), stream);
  hipMemsetAsync(out, 0, sizeof(float), stream);

  normalize_kernel<<<NROWS / 4, 256, 0, stream>>>(h1, h2, zb);
  dim3 grid(64, 64);
  simexp_kernel<<<grid, 256, 0, stream>>>(zb, rowsum);
  finalize_kernel<<<NROWS / 4, 256, 0, stream>>>(zb, rowsum, out);
}

// Round 2
// 152.049 us; speedup vs baseline: 2.0319x; 2.0319x over previous
//
#include <hip/hip_runtime.h>
#include <hip/hip_bf16.h>

typedef __bf16 bf16x8 __attribute__((ext_vector_type(8)));
typedef float  f32x4  __attribute__((ext_vector_type(4)));

#define B_ROWS 4096
#define NROWS  8192
#define DDIM   512
// exp(sim/T) = exp2(sim * (1/T)/ln2), T=0.5 -> 2/ln2
#define SCALE2 2.8853900817779268f

// ---------------- normalize: fp32 rows -> bf16 normalized rows in ws ----------------
// Also zero-inits rowsum[] and out[] (replaces memset nodes).
__global__ __launch_bounds__(256) void normalize_kernel(
    const float* __restrict__ h1, const float* __restrict__ h2,
    __bf16* __restrict__ zb, float* __restrict__ rowsum, float* __restrict__ out) {
  int gid = blockIdx.x * 256 + threadIdx.x;
  if (gid < NROWS) rowsum[gid] = 0.0f;
  if (gid == 0) out[0] = 0.0f;

  int wave = threadIdx.x >> 6;
  int lane = threadIdx.x & 63;
  int row  = blockIdx.x * 4 + wave;
  const float* src = (row < B_ROWS) ? (h1 + (size_t)row * DDIM)
                                    : (h2 + (size_t)(row - B_ROWS) * DDIM);
  float4 v0 = *(const float4*)(src + lane * 8);
  float4 v1 = *(const float4*)(src + lane * 8 + 4);
  float ss = v0.x*v0.x + v0.y*v0.y + v0.z*v0.z + v0.w*v0.w
           + v1.x*v1.x + v1.y*v1.y + v1.z*v1.z + v1.w*v1.w;
  #pragma unroll
  for (int m = 1; m <= 32; m <<= 1) ss += __shfl_xor(ss, m);
  float scale = 1.0f / fmaxf(sqrtf(ss), 1e-8f);
  bf16x8 o;
  o[0] = (__bf16)(v0.x*scale); o[1] = (__bf16)(v0.y*scale);
  o[2] = (__bf16)(v0.z*scale); o[3] = (__bf16)(v0.w*scale);
  o[4] = (__bf16)(v1.x*scale); o[5] = (__bf16)(v1.y*scale);
  o[6] = (__bf16)(v1.z*scale); o[7] = (__bf16)(v1.w*scale);
  *(bf16x8*)(zb + (size_t)row * DDIM + lane * 8) = o;
}

// ---------------- fused sim GEMM + exp + row-sum, lower-triangle blocks only --------
// grid.x = 2080 = 64*65/2 triangular 128x128 blocks. Off-diagonal blocks emit both
// row-sums (rows of bi) and col-sums (rows of bj, by symmetry e_rc == e_cr).
// LDS layout XOR-swizzled: row r's k-quad q stored at slot q ^ ((r>>1)&3) so
// fragment ds_read_b128 is 2-way aliased (free) instead of 8-way.
__global__ __launch_bounds__(256) void simexp_kernel(
    const __bf16* __restrict__ zb, float* __restrict__ rowsum) {
  __shared__ __align__(16) __bf16 As[128 * 32];
  __shared__ __align__(16) __bf16 Bs[128 * 32];

  const int tid  = threadIdx.x;
  const int wave = tid >> 6;
  const int lane = tid & 63;
  const int wm = wave >> 1, wn = wave & 1;
  const int quad = lane >> 4;
  const int l16  = lane & 15;

  // unrank triangular block index: t = bi*(bi+1)/2 + bj, bi >= bj
  int t  = blockIdx.x;
  int bi = (int)((sqrtf(8.0f * (float)t + 1.0f) - 1.0f) * 0.5f);
  while ((bi + 1) * (bi + 2) / 2 <= t) ++bi;
  while (bi * (bi + 1) / 2 > t) --bi;
  int bj = t - bi * (bi + 1) / 2;
  const int rowBlk = bi * 128;
  const int colBlk = bj * 128;
  const bool isDiag = (bi == bj);

  // staging: lane l loads row (l>>2), global k-quad ((l&3) ^ ((srow>>1)&3)) so the
  // fixed lane*16 LDS destination realizes the swizzled layout.
  const int srow = lane >> 2;
  const int sq   = (lane & 3) ^ ((srow >> 1) & 3);
  const int scol = sq * 8;

  f32x4 acc[4][4] = {};

  #pragma unroll 1
  for (int kt = 0; kt < 16; ++kt) {
    const int k0 = kt * 32;
    #pragma unroll
    for (int q = 0; q < 2; ++q) {
      const int rl = wave * 32 + q * 16;  // wave-uniform chunk base (16 rows)
      const __bf16* ga = zb + (size_t)(rowBlk + rl + srow) * DDIM + k0 + scol;
      const __bf16* gb = zb + (size_t)(colBlk + rl + srow) * DDIM + k0 + scol;
      __builtin_amdgcn_global_load_lds(
          (const __attribute__((address_space(1))) unsigned int*)ga,
          (__attribute__((address_space(3))) unsigned int*)(As + rl * 32), 16, 0, 0);
      __builtin_amdgcn_global_load_lds(
          (const __attribute__((address_space(1))) unsigned int*)gb,
          (__attribute__((address_space(3))) unsigned int*)(Bs + rl * 32), 16, 0, 0);
    }
    __syncthreads();

    bf16x8 afr[4], bfr[4];
    #pragma unroll
    for (int rt = 0; rt < 4; ++rt) {
      const int lr = wm * 64 + rt * 16 + l16;
      afr[rt] = *(const bf16x8*)(As + lr * 32 + (quad ^ ((lr >> 1) & 3)) * 8);
    }
    #pragma unroll
    for (int ct = 0; ct < 4; ++ct) {
      const int lr = wn * 64 + ct * 16 + l16;
      bfr[ct] = *(const bf16x8*)(Bs + lr * 32 + (quad ^ ((lr >> 1) & 3)) * 8);
    }
    #pragma unroll
    for (int rt = 0; rt < 4; ++rt)
      #pragma unroll
      for (int ct = 0; ct < 4; ++ct)
        acc[rt][ct] = __builtin_amdgcn_mfma_f32_16x16x32_bf16(
            afr[rt], bfr[ct], acc[rt][ct], 0, 0, 0);
    __syncthreads();
  }

  // epilogue: e = exp2(sim*SCALE2); C/D layout: col = lane&15, row = quad*4 + reg
  float colpart[4] = {0.f, 0.f, 0.f, 0.f};
  #pragma unroll
  for (int rt = 0; rt < 4; ++rt) {
    #pragma unroll
    for (int r = 0; r < 4; ++r) {
      const int grow = rowBlk + wm * 64 + rt * 16 + quad * 4 + r;
      float s = 0.f;
      #pragma unroll
      for (int ct = 0; ct < 4; ++ct) {
        const int gcol = colBlk + wn * 64 + ct * 16 + l16;
        float e = exp2f(acc[rt][ct][r] * SCALE2);
        if (isDiag && grow == gcol) e = 0.f;
        s += e;
        colpart[ct] += e;
      }
      s += __shfl_xor(s, 1);
      s += __shfl_xor(s, 2);
      s += __shfl_xor(s, 4);
      s += __shfl_xor(s, 8);
      if (l16 == 0) atomicAdd(&rowsum[grow], s);
    }
  }
  if (!isDiag) {
    #pragma unroll
    for (int ct = 0; ct < 4; ++ct) {
      float c = colpart[ct];
      c += __shfl_xor(c, 16);
      c += __shfl_xor(c, 32);
      if (quad == 0)
        atomicAdd(&rowsum[colBlk + wn * 64 + ct * 16 + l16], c);
    }
  }
}

// ---------------- finalize: loss_i = ln(rowsum_i) - 2*pos_i ; mean ----------------
// 128 blocks, grid-stride by wave; per-block LDS reduce -> 128 total atomics.
__global__ __launch_bounds__(256) void finalize_kernel(
    const __bf16* __restrict__ zb, const float* __restrict__ rowsum,
    float* __restrict__ out) {
  __shared__ float wsum[4];
  const int wave = threadIdx.x >> 6;
  const int lane = threadIdx.x & 63;
  float accl = 0.f;
  for (int row = blockIdx.x * 4 + wave; row < NROWS; row += gridDim.x * 4) {
    int partner = (row + B_ROWS) & (NROWS - 1);
    bf16x8 va = *(const bf16x8*)(zb + (size_t)row * DDIM + lane * 8);
    bf16x8 vb = *(const bf16x8*)(zb + (size_t)partner * DDIM + lane * 8);
    float dot = 0.f;
    #pragma unroll
    for (int j = 0; j < 8; ++j) dot += (float)va[j] * (float)vb[j];
    #pragma unroll
    for (int m = 1; m <= 32; m <<= 1) dot += __shfl_xor(dot, m);
    if (lane == 0) accl += __logf(rowsum[row]) - 2.0f * dot;
  }
  if (lane == 0) wsum[wave] = accl;
  __syncthreads();
  if (threadIdx.x == 0) {
    float s = wsum[0] + wsum[1] + wsum[2] + wsum[3];
    atomicAdd(out, s * (1.0f / NROWS));
  }
}

extern "C" void kernel_launch(void* const* d_in, const int* in_sizes, int n_in,
                              void* d_out, int out_size, void* d_ws, size_t ws_size,
                              hipStream_t stream) {
  const float* h1 = (const float*)d_in[0];
  const float* h2 = (const float*)d_in[1];
  float* out = (float*)d_out;
  __bf16* zb = (__bf16*)d_ws;                                        // 8 MiB
  float* rowsum = (float*)((char*)d_ws + (size_t)NROWS * DDIM * 2);  // 32 KiB

  normalize_kernel<<<NROWS / 4, 256, 0, stream>>>(h1, h2, zb, rowsum, out);
  simexp_kernel<<<64 * 65 / 2, 256, 0, stream>>>(zb, rowsum);
  finalize_kernel<<<128, 256, 0, stream>>>(zb, rowsum, out);
}